// Round 4
// baseline (277.196 us; speedup 1.0000x reference)
//
#include <hip/hip_runtime.h>
#include <math.h>

typedef __attribute__((ext_vector_type(8))) short short8;
typedef __attribute__((ext_vector_type(4))) float f32x4;

constexpr int B   = 4;
constexpr int N   = 2304;
constexpr int DIM = 256;
constexpr int NH  = 8;
constexpr int DH  = 32;
constexpr int M   = B * N;        // 9216 rows

// float -> bf16 round-to-nearest-even, and back
__device__ inline unsigned short f2bf(float f) {
    union { float f; unsigned u; } c; c.f = f;
    unsigned u = c.u;
    u += 0x7fffu + ((u >> 16) & 1u);
    return (unsigned short)(u >> 16);
}
__device__ inline float bf2f(unsigned short h) {
    union { unsigned u; float f; } c; c.u = ((unsigned)h) << 16;
    return c.f;
}

// ---------------- LayerNorm -> hi/lo bf16 split, one block per row ---------
__global__ __launch_bounds__(256) void ln_kernel(
    const float* __restrict__ x, const float* __restrict__ g,
    const float* __restrict__ bta,
    unsigned short* __restrict__ xh, unsigned short* __restrict__ xl)
{
    __shared__ float red[4];
    int row = blockIdx.x;
    int t   = threadIdx.x;
    float v = x[(size_t)row * DIM + t];
    float s = v;
    #pragma unroll
    for (int o = 32; o > 0; o >>= 1) s += __shfl_down(s, o, 64);
    if ((t & 63) == 0) red[t >> 6] = s;
    __syncthreads();
    float mu = (red[0] + red[1] + red[2] + red[3]) * (1.0f / DIM);
    __syncthreads();
    float d  = v - mu;
    float s2 = d * d;
    #pragma unroll
    for (int o = 32; o > 0; o >>= 1) s2 += __shfl_down(s2, o, 64);
    if ((t & 63) == 0) red[t >> 6] = s2;
    __syncthreads();
    float var = (red[0] + red[1] + red[2] + red[3]) * (1.0f / DIM);
    float r   = rsqrtf(var + 1e-5f);
    float y   = d * r * g[t] + bta[t];
    unsigned short hh = f2bf(y);
    xh[(size_t)row * DIM + t] = hh;
    xl[(size_t)row * DIM + t] = f2bf(y - bf2f(hh));
}

// ---------------- W (256x256 fp32) -> W^T hi/lo bf16 -----------------------
__global__ __launch_bounds__(256) void split_w(
    const float* __restrict__ W,
    unsigned short* __restrict__ Wt_hi, unsigned short* __restrict__ Wt_lo)
{
    __shared__ float t[32][33];
    int tid = threadIdx.x;
    int tx = tid & 31, ty0 = tid >> 5;
    int n0 = blockIdx.x * 32, k0 = blockIdx.y * 32;
    for (int ty = ty0; ty < 32; ty += 8)
        t[ty][tx] = W[(size_t)(k0 + ty) * DIM + n0 + tx];
    __syncthreads();
    for (int ty = ty0; ty < 32; ty += 8) {
        float v = t[tx][ty];                 // = W[k0+tx][n0+ty]
        unsigned short hh = f2bf(v);
        size_t o = (size_t)(n0 + ty) * DIM + k0 + tx;
        Wt_hi[o] = hh;
        Wt_lo[o] = f2bf(v - bf2f(hh));
    }
}

// ---------------- split-bf16 MFMA GEMM: C = A @ W + bias -------------------
// A as hi/lo bf16 row-major [M x 256]; W as W^T hi/lo bf16 [256 x 256].
// ah*bh + ah*bl + al*bh: ~fp32 accuracy (residual ~2^-18 rel).
// Wave: 32 rows x 32 cols; block 4 waves = 128 rows x 32 cols.
// LAYOUT 0: fp32 row-major out[r*256+c]              (final projection)
// LAYOUT 1: bf16 QK scatter out[((b*8+h)*N+n)*32+d]  (attn A/B-frag layout)
template<int LAYOUT>
__global__ __launch_bounds__(256) void mfma_gemm(
    const unsigned short* __restrict__ Ahi, const unsigned short* __restrict__ Alo,
    const unsigned short* __restrict__ Bhi, const unsigned short* __restrict__ Blo,
    const float* __restrict__ bias, void* __restrict__ out_v)
{
    int tid = threadIdx.x;
    int wave = tid >> 6, lane = tid & 63;
    int quad = lane >> 4, l16 = lane & 15;
    int r0 = blockIdx.y * 128 + wave * 32;
    int c0 = blockIdx.x * 32;
    f32x4 acc[2][2] = {};
    for (int k0 = 0; k0 < DIM; k0 += 32) {
        size_t ao0 = (size_t)(r0 + l16) * DIM + k0 + quad * 8;
        size_t ao1 = (size_t)(r0 + 16 + l16) * DIM + k0 + quad * 8;
        short8 ah0 = *(const short8*)&Ahi[ao0];
        short8 al0 = *(const short8*)&Alo[ao0];
        short8 ah1 = *(const short8*)&Ahi[ao1];
        short8 al1 = *(const short8*)&Alo[ao1];
        #pragma unroll
        for (int j = 0; j < 2; ++j) {
            size_t bo = (size_t)(c0 + j * 16 + l16) * DIM + k0 + quad * 8;
            short8 bh = *(const short8*)&Bhi[bo];
            short8 bl = *(const short8*)&Blo[bo];
            acc[0][j] = __builtin_amdgcn_mfma_f32_16x16x32_bf16(ah0, bh, acc[0][j], 0, 0, 0);
            acc[0][j] = __builtin_amdgcn_mfma_f32_16x16x32_bf16(ah0, bl, acc[0][j], 0, 0, 0);
            acc[0][j] = __builtin_amdgcn_mfma_f32_16x16x32_bf16(al0, bh, acc[0][j], 0, 0, 0);
            acc[1][j] = __builtin_amdgcn_mfma_f32_16x16x32_bf16(ah1, bh, acc[1][j], 0, 0, 0);
            acc[1][j] = __builtin_amdgcn_mfma_f32_16x16x32_bf16(ah1, bl, acc[1][j], 0, 0, 0);
            acc[1][j] = __builtin_amdgcn_mfma_f32_16x16x32_bf16(al1, bh, acc[1][j], 0, 0, 0);
        }
    }
    #pragma unroll
    for (int i = 0; i < 2; ++i)
    #pragma unroll
    for (int j = 0; j < 2; ++j) {
        int c = c0 + j * 16 + l16;
        float bs = bias[c];
        #pragma unroll
        for (int r = 0; r < 4; ++r) {
            int R = r0 + i * 16 + quad * 4 + r;
            float vvv = acc[i][j][r] + bs;
            if (LAYOUT == 0) {
                ((float*)out_v)[(size_t)R * DIM + c] = vvv;
            } else {
                int b = R / N, n = R - b * N;
                int h = c >> 5, d = c & 31;
                ((unsigned short*)out_v)[(((size_t)(b * NH + h)) * N + n) * DH + d] = f2bf(vvv);
            }
        }
    }
}

// ---------------- split-bf16 MFMA GEMM computing V^T directly --------------
// D[m=c][n=row] = sum_k Wt[c][k] * A[row][k]  -> out[((b*8+h)*32+d)*N+n]
// m-tiles come from W^T (A-operand), n-tiles from xn (B-operand); the
// 16-lane n-run makes the V^T store contiguous.
__global__ __launch_bounds__(256) void mfma_gemm_vt(
    const unsigned short* __restrict__ Ahi, const unsigned short* __restrict__ Alo,
    const unsigned short* __restrict__ Bhi, const unsigned short* __restrict__ Blo,
    const float* __restrict__ bias, unsigned short* __restrict__ out)
{
    int tid = threadIdx.x;
    int wave = tid >> 6, lane = tid & 63;
    int quad = lane >> 4, l16 = lane & 15;
    int m0 = blockIdx.y * 128 + wave * 32;   // over c (256)
    int n0 = blockIdx.x * 32;                // over rows (9216)
    f32x4 acc[2][2] = {};
    for (int k0 = 0; k0 < DIM; k0 += 32) {
        size_t wo0 = (size_t)(m0 + l16) * DIM + k0 + quad * 8;
        size_t wo1 = (size_t)(m0 + 16 + l16) * DIM + k0 + quad * 8;
        short8 ah0 = *(const short8*)&Bhi[wo0];   // Wt hi (A-operand)
        short8 al0 = *(const short8*)&Blo[wo0];
        short8 ah1 = *(const short8*)&Bhi[wo1];
        short8 al1 = *(const short8*)&Blo[wo1];
        #pragma unroll
        for (int j = 0; j < 2; ++j) {
            size_t xo = (size_t)(n0 + j * 16 + l16) * DIM + k0 + quad * 8;
            short8 bh = *(const short8*)&Ahi[xo]; // xn hi (B-operand)
            short8 bl = *(const short8*)&Alo[xo];
            acc[0][j] = __builtin_amdgcn_mfma_f32_16x16x32_bf16(ah0, bh, acc[0][j], 0, 0, 0);
            acc[0][j] = __builtin_amdgcn_mfma_f32_16x16x32_bf16(ah0, bl, acc[0][j], 0, 0, 0);
            acc[0][j] = __builtin_amdgcn_mfma_f32_16x16x32_bf16(al0, bh, acc[0][j], 0, 0, 0);
            acc[1][j] = __builtin_amdgcn_mfma_f32_16x16x32_bf16(ah1, bh, acc[1][j], 0, 0, 0);
            acc[1][j] = __builtin_amdgcn_mfma_f32_16x16x32_bf16(ah1, bl, acc[1][j], 0, 0, 0);
            acc[1][j] = __builtin_amdgcn_mfma_f32_16x16x32_bf16(al1, bh, acc[1][j], 0, 0, 0);
        }
    }
    #pragma unroll
    for (int i = 0; i < 2; ++i)
    #pragma unroll
    for (int r = 0; r < 4; ++r) {
        int c = m0 + i * 16 + quad * 4 + r;
        int h = c >> 5, d = c & 31;
        float bs = bias[c];
        #pragma unroll
        for (int j = 0; j < 2; ++j) {
            int R = n0 + j * 16 + l16;
            int b = R / N, n = R - b * N;
            out[((size_t)(b * NH + h) * DH + d) * N + n] = f2bf(acc[i][j][r] + bs);
        }
    }
}

// ---------------- MFMA flash attention (R2 structure) ----------------------
// Epilogue now writes hi/lo bf16 for the split-bf16 final projection.
__global__ __launch_bounds__(256) void attn_kernel(
    const unsigned short* __restrict__ Qb,
    const unsigned short* __restrict__ Kb,
    const unsigned short* __restrict__ Vt,
    const float* __restrict__ mask,
    unsigned short* __restrict__ ahn_hi, unsigned short* __restrict__ ahn_lo)
{
    __shared__ unsigned short pbuf[8 * 16 * 40];   // (wave,tile) x 16 x 40
    int tid  = threadIdx.x;
    int wave = tid >> 6, lane = tid & 63;
    int quad = lane >> 4, l16 = lane & 15;
    int bh = blockIdx.y, b = bh >> 3, h = bh & 7;
    int q0 = (blockIdx.x * 4 + wave) * 32;

    const size_t nb = (size_t)bh * N;
    short8 qA0 = *(const short8*)&Qb[(nb + q0 + l16) * DH + quad * 8];
    short8 qA1 = *(const short8*)&Qb[(nb + q0 + 16 + l16) * DH + quad * 8];

    f32x4 o00 = {0,0,0,0}, o01 = {0,0,0,0}, o10 = {0,0,0,0}, o11 = {0,0,0,0};
    float l0[4] = {0,0,0,0}, l1[4] = {0,0,0,0};

    unsigned short* pb0 = &pbuf[(wave * 2 + 0) * 640];
    unsigned short* pb1 = &pbuf[(wave * 2 + 1) * 640];
    const float* mb = mask + (size_t)b * N;
    const unsigned short* vtb = Vt + (size_t)bh * DH * N;

    for (int k0 = 0; k0 < N; k0 += 32) {
        short8 kB0 = *(const short8*)&Kb[(nb + k0 + l16) * DH + quad * 8];
        short8 kB1 = *(const short8*)&Kb[(nb + k0 + 16 + l16) * DH + quad * 8];
        float m0 = mb[k0 + l16] > 0.f ? 1.f : 0.f;
        float m1 = mb[k0 + 16 + l16] > 0.f ? 1.f : 0.f;
        f32x4 z = {0,0,0,0};
        f32x4 s00 = __builtin_amdgcn_mfma_f32_16x16x32_bf16(qA0, kB0, z, 0, 0, 0);
        f32x4 s01 = __builtin_amdgcn_mfma_f32_16x16x32_bf16(qA0, kB1, z, 0, 0, 0);
        f32x4 s10 = __builtin_amdgcn_mfma_f32_16x16x32_bf16(qA1, kB0, z, 0, 0, 0);
        f32x4 s11 = __builtin_amdgcn_mfma_f32_16x16x32_bf16(qA1, kB1, z, 0, 0, 0);
        #pragma unroll
        for (int r = 0; r < 4; ++r) {
            int row = quad * 4 + r;
            float p00 = __expf(s00[r] * m0), p01 = __expf(s01[r] * m1);
            float p10 = __expf(s10[r] * m0), p11 = __expf(s11[r] * m1);
            l0[r] += p00 + p01;
            l1[r] += p10 + p11;
            pb0[row * 40 + l16]      = f2bf(p00);
            pb0[row * 40 + 16 + l16] = f2bf(p01);
            pb1[row * 40 + l16]      = f2bf(p10);
            pb1[row * 40 + 16 + l16] = f2bf(p11);
        }
        short8 vB0 = *(const short8*)&vtb[(size_t)(l16)      * N + k0 + quad * 8];
        short8 vB1 = *(const short8*)&vtb[(size_t)(16 + l16) * N + k0 + quad * 8];
        short8 pA0 = *(const short8*)&pb0[l16 * 40 + quad * 8];
        short8 pA1 = *(const short8*)&pb1[l16 * 40 + quad * 8];
        o00 = __builtin_amdgcn_mfma_f32_16x16x32_bf16(pA0, vB0, o00, 0, 0, 0);
        o01 = __builtin_amdgcn_mfma_f32_16x16x32_bf16(pA0, vB1, o01, 0, 0, 0);
        o10 = __builtin_amdgcn_mfma_f32_16x16x32_bf16(pA1, vB0, o10, 0, 0, 0);
        o11 = __builtin_amdgcn_mfma_f32_16x16x32_bf16(pA1, vB1, o11, 0, 0, 0);
    }
    #pragma unroll
    for (int r = 0; r < 4; ++r) {
        #pragma unroll
        for (int off = 1; off < 16; off <<= 1) {
            l0[r] += __shfl_xor(l0[r], off, 64);
            l1[r] += __shfl_xor(l1[r], off, 64);
        }
    }
    #pragma unroll
    for (int r = 0; r < 4; ++r) {
        int row = quad * 4 + r;
        float inv0 = 1.f / l0[r], inv1 = 1.f / l1[r];
        size_t R0 = (size_t)(b * N + q0 + row) * DIM + h * DH;
        size_t R1 = (size_t)(b * N + q0 + 16 + row) * DIM + h * DH;
        float v00 = o00[r] * inv0, v01 = o01[r] * inv0;
        float v10 = o10[r] * inv1, v11 = o11[r] * inv1;
        unsigned short t;
        t = f2bf(v00); ahn_hi[R0 + l16]      = t; ahn_lo[R0 + l16]      = f2bf(v00 - bf2f(t));
        t = f2bf(v01); ahn_hi[R0 + 16 + l16] = t; ahn_lo[R0 + 16 + l16] = f2bf(v01 - bf2f(t));
        t = f2bf(v10); ahn_hi[R1 + l16]      = t; ahn_lo[R1 + l16]      = f2bf(v10 - bf2f(t));
        t = f2bf(v11); ahn_hi[R1 + 16 + l16] = t; ahn_lo[R1 + 16 + l16] = f2bf(v11 - bf2f(t));
    }
}

extern "C" void kernel_launch(void* const* d_in, const int* in_sizes, int n_in,
                              void* d_out, int out_size, void* d_ws, size_t ws_size,
                              hipStream_t stream)
{
    const float* x    = (const float*)d_in[0];
    const float* mask = (const float*)d_in[1];
    const float* ln_g = (const float*)d_in[2];
    const float* ln_b = (const float*)d_in[3];
    const float* Wq   = (const float*)d_in[4];
    const float* bq   = (const float*)d_in[5];
    const float* Wk   = (const float*)d_in[6];
    const float* bk   = (const float*)d_in[7];
    const float* Wv   = (const float*)d_in[8];
    const float* bv   = (const float*)d_in[9];
    const float* Wp   = (const float*)d_in[10];
    const float* bp   = (const float*)d_in[11];
    float* out = (float*)d_out;

    constexpr size_t SZ  = (size_t)M * DIM;   // 2359296 elements
    constexpr size_t WSZ = (size_t)DIM * DIM; // 65536
    unsigned short* p = (unsigned short*)d_ws;
    unsigned short* xh = p;  p += SZ;
    unsigned short* xl = p;  p += SZ;
    unsigned short* qb = p;  p += SZ;
    unsigned short* kb = p;  p += SZ;
    unsigned short* vt = p;  p += SZ;
    unsigned short* ah = p;  p += SZ;   // attn out hi
    unsigned short* al = p;  p += SZ;   // attn out lo
    unsigned short* wqh = p; p += WSZ;  unsigned short* wql = p; p += WSZ;
    unsigned short* wkh = p; p += WSZ;  unsigned short* wkl = p; p += WSZ;
    unsigned short* wvh = p; p += WSZ;  unsigned short* wvl = p; p += WSZ;
    unsigned short* wph = p; p += WSZ;  unsigned short* wpl = p; p += WSZ;

    ln_kernel<<<M, 256, 0, stream>>>(x, ln_g, ln_b, xh, xl);

    dim3 wgrid(8, 8);
    split_w<<<wgrid, 256, 0, stream>>>(Wq, wqh, wql);
    split_w<<<wgrid, 256, 0, stream>>>(Wk, wkh, wkl);
    split_w<<<wgrid, 256, 0, stream>>>(Wv, wvh, wvl);
    split_w<<<wgrid, 256, 0, stream>>>(Wp, wph, wpl);

    dim3 ggrid(DIM / 32, M / 128);   // (8, 72) = 576 blocks
    mfma_gemm<1><<<ggrid, 256, 0, stream>>>(xh, xl, wqh, wql, bq, qb);
    mfma_gemm<1><<<ggrid, 256, 0, stream>>>(xh, xl, wkh, wkl, bk, kb);
    dim3 vgrid(M / 32, DIM / 128);   // (288, 2) = 576 blocks
    mfma_gemm_vt<<<vgrid, 256, 0, stream>>>(xh, xl, wvh, wvl, bv, vt);

    dim3 agrid(N / 128, B * NH);     // (18, 32): 4 waves/block, 32 q/wave
    attn_kernel<<<agrid, 256, 0, stream>>>(qb, kb, vt, mask, ah, al);

    mfma_gemm<0><<<ggrid, 256, 0, stream>>>(ah, al, wph, wpl, bp, out);
}

// Round 5
// 215.229 us; speedup vs baseline: 1.2879x; 1.2879x over previous
//
#include <hip/hip_runtime.h>
#include <math.h>

typedef __attribute__((ext_vector_type(8))) short short8;
typedef __attribute__((ext_vector_type(4))) float f32x4;

constexpr int B   = 4;
constexpr int N   = 2304;
constexpr int DIM = 256;
constexpr int NH  = 8;
constexpr int DH  = 32;
constexpr int M   = B * N;        // 9216 rows

// float -> bf16 round-to-nearest-even, and back
__device__ inline unsigned short f2bf(float f) {
    union { float f; unsigned u; } c; c.f = f;
    unsigned u = c.u;
    u += 0x7fffu + ((u >> 16) & 1u);
    return (unsigned short)(u >> 16);
}
__device__ inline float bf2f(unsigned short h) {
    union { unsigned u; float f; } c; c.u = ((unsigned)h) << 16;
    return c.f;
}

// ---- FragTile layouts: element (row r, contraction k) stored so an MFMA
// A/B-frag load (16 rows x 32 k) is ONE contiguous 1KB wave transaction:
// lane = (k%32/8)*16 + r%16 (hw lane = quad*16+l16), elem j = k%8.
// [R x 256] tensors (xn, W^T, attn-out):
__device__ inline size_t fo256(int r, int k) {
    return ((size_t)((r >> 4) * 8 + (k >> 5)) << 9)
         + (size_t)(((((k & 31) >> 3) << 4) + (r & 15)) * 8 + (k & 7));
}
// per-(b,h) Q/K: [N x 32] (r=n, k=d)
__device__ inline size_t foQK(int n, int d) {
    return ((size_t)(n >> 4) << 9)
         + (size_t)((((d >> 3) << 4) + (n & 15)) * 8 + (d & 7));
}
// per-(b,h) V^T: [32 x N] (r=d, k=key)
__device__ inline size_t foVT(int d, int key) {
    return ((size_t)((d >> 4) * (N / 32) + (key >> 5)) << 9)
         + (size_t)(((((key & 31) >> 3) << 4) + (d & 15)) * 8 + (key & 7));
}

// ---------------- LayerNorm -> hi/lo bf16 FragTile, one block per row ------
__global__ __launch_bounds__(256) void ln_kernel(
    const float* __restrict__ x, const float* __restrict__ g,
    const float* __restrict__ bta,
    unsigned short* __restrict__ xh, unsigned short* __restrict__ xl)
{
    __shared__ float red[4];
    int row = blockIdx.x;
    int t   = threadIdx.x;
    float v = x[(size_t)row * DIM + t];
    float s = v;
    #pragma unroll
    for (int o = 32; o > 0; o >>= 1) s += __shfl_down(s, o, 64);
    if ((t & 63) == 0) red[t >> 6] = s;
    __syncthreads();
    float mu = (red[0] + red[1] + red[2] + red[3]) * (1.0f / DIM);
    __syncthreads();
    float d  = v - mu;
    float s2 = d * d;
    #pragma unroll
    for (int o = 32; o > 0; o >>= 1) s2 += __shfl_down(s2, o, 64);
    if ((t & 63) == 0) red[t >> 6] = s2;
    __syncthreads();
    float var = (red[0] + red[1] + red[2] + red[3]) * (1.0f / DIM);
    float r   = rsqrtf(var + 1e-5f);
    float y   = d * r * g[t] + bta[t];
    unsigned short hh = f2bf(y);
    size_t o = fo256(row, t);
    xh[o] = hh;
    xl[o] = f2bf(y - bf2f(hh));
}

// ---------------- all 4 W (256x256 fp32) -> W^T hi/lo FragTile -------------
__global__ __launch_bounds__(256) void split_w(
    const float* __restrict__ Wq, const float* __restrict__ Wk,
    const float* __restrict__ Wv, const float* __restrict__ Wp,
    unsigned short* __restrict__ Wth, unsigned short* __restrict__ Wtl)
{
    int z = blockIdx.z;
    const float* W = (z == 0) ? Wq : (z == 1) ? Wk : (z == 2) ? Wv : Wp;
    unsigned short* oh = Wth + (size_t)z * DIM * DIM;
    unsigned short* ol = Wtl + (size_t)z * DIM * DIM;
    __shared__ float t[32][33];
    int tid = threadIdx.x;
    int tx = tid & 31, ty0 = tid >> 5;
    int n0 = blockIdx.x * 32, k0 = blockIdx.y * 32;
    for (int ty = ty0; ty < 32; ty += 8)
        t[ty][tx] = W[(size_t)(k0 + ty) * DIM + n0 + tx];
    __syncthreads();
    for (int nn = ty0; nn < 32; nn += 8) {
        float v = t[tx][nn];                 // = W[k0+tx][n0+nn] = Wt[n][k]
        unsigned short hh = f2bf(v);
        size_t o = fo256(n0 + nn, k0 + tx);
        oh[o] = hh;
        ol[o] = f2bf(v - bf2f(hh));
    }
}

// ---------------- split-bf16 MFMA GEMM, FragTile operands ------------------
// z=0: Q (bias bq -> qb), z=1: K (bias bk -> kb). Wave: 32 rows x 32 cols.
__global__ __launch_bounds__(256) void gemm_qk(
    const unsigned short* __restrict__ Ahi, const unsigned short* __restrict__ Alo,
    const unsigned short* __restrict__ Wth, const unsigned short* __restrict__ Wtl,
    const float* __restrict__ bq, const float* __restrict__ bk,
    unsigned short* __restrict__ qb, unsigned short* __restrict__ kb)
{
    int z = blockIdx.z;
    const unsigned short* Bhi = Wth + (size_t)z * DIM * DIM;
    const unsigned short* Blo = Wtl + (size_t)z * DIM * DIM;
    const float* bias = z ? bk : bq;
    unsigned short* out = z ? kb : qb;
    int tid = threadIdx.x;
    int wave = tid >> 6, lane = tid & 63;
    int quad = lane >> 4, l16 = lane & 15;
    int r0 = blockIdx.y * 128 + wave * 32;
    int c0 = blockIdx.x * 32;
    f32x4 acc[2][2] = {};
    for (int k0 = 0; k0 < DIM; k0 += 32) {
        size_t at = (((size_t)(r0 >> 4) * 8 + (k0 >> 5)) << 9) + lane * 8;
        size_t bt = (((size_t)(c0 >> 4) * 8 + (k0 >> 5)) << 9) + lane * 8;
        short8 ah0 = *(const short8*)&Ahi[at];
        short8 al0 = *(const short8*)&Alo[at];
        short8 ah1 = *(const short8*)&Ahi[at + 4096];
        short8 al1 = *(const short8*)&Alo[at + 4096];
        short8 bh0 = *(const short8*)&Bhi[bt];
        short8 bl0 = *(const short8*)&Blo[bt];
        short8 bh1 = *(const short8*)&Bhi[bt + 4096];
        short8 bl1 = *(const short8*)&Blo[bt + 4096];
        acc[0][0] = __builtin_amdgcn_mfma_f32_16x16x32_bf16(ah0, bh0, acc[0][0], 0, 0, 0);
        acc[0][0] = __builtin_amdgcn_mfma_f32_16x16x32_bf16(ah0, bl0, acc[0][0], 0, 0, 0);
        acc[0][0] = __builtin_amdgcn_mfma_f32_16x16x32_bf16(al0, bh0, acc[0][0], 0, 0, 0);
        acc[0][1] = __builtin_amdgcn_mfma_f32_16x16x32_bf16(ah0, bh1, acc[0][1], 0, 0, 0);
        acc[0][1] = __builtin_amdgcn_mfma_f32_16x16x32_bf16(ah0, bl1, acc[0][1], 0, 0, 0);
        acc[0][1] = __builtin_amdgcn_mfma_f32_16x16x32_bf16(al0, bh1, acc[0][1], 0, 0, 0);
        acc[1][0] = __builtin_amdgcn_mfma_f32_16x16x32_bf16(ah1, bh0, acc[1][0], 0, 0, 0);
        acc[1][0] = __builtin_amdgcn_mfma_f32_16x16x32_bf16(ah1, bl0, acc[1][0], 0, 0, 0);
        acc[1][0] = __builtin_amdgcn_mfma_f32_16x16x32_bf16(al1, bh0, acc[1][0], 0, 0, 0);
        acc[1][1] = __builtin_amdgcn_mfma_f32_16x16x32_bf16(ah1, bh1, acc[1][1], 0, 0, 0);
        acc[1][1] = __builtin_amdgcn_mfma_f32_16x16x32_bf16(ah1, bl1, acc[1][1], 0, 0, 0);
        acc[1][1] = __builtin_amdgcn_mfma_f32_16x16x32_bf16(al1, bh1, acc[1][1], 0, 0, 0);
    }
    int b = r0 / N;                      // uniform: r0 mult of 32, 2304 mult of 32
    int nbase = r0 - b * N;
    #pragma unroll
    for (int j = 0; j < 2; ++j) {
        int c = c0 + j * 16 + l16;
        int h = c >> 5, d = c & 31;
        float bs = bias[c];
        unsigned short* ob = out + (size_t)(b * NH + h) * ((size_t)N * DH);
        #pragma unroll
        for (int i = 0; i < 2; ++i)
        #pragma unroll
        for (int r = 0; r < 4; ++r) {
            int n = nbase + i * 16 + quad * 4 + r;
            ob[foQK(n, d)] = f2bf(acc[i][j][r] + bs);
        }
    }
}

// ---------------- V GEMM computing V^T FragTile directly -------------------
// C[m=c][n=xrow]: A = Wv^T FragTile, B = xn FragTile.
__global__ __launch_bounds__(256) void gemm_v(
    const unsigned short* __restrict__ Ahi, const unsigned short* __restrict__ Alo,
    const unsigned short* __restrict__ Wth, const unsigned short* __restrict__ Wtl,
    const float* __restrict__ bias, unsigned short* __restrict__ vt)
{
    const unsigned short* Vhi = Wth + (size_t)2 * DIM * DIM;
    const unsigned short* Vlo = Wtl + (size_t)2 * DIM * DIM;
    int tid = threadIdx.x;
    int wave = tid >> 6, lane = tid & 63;
    int quad = lane >> 4, l16 = lane & 15;
    int m0 = blockIdx.y * 128 + wave * 32;   // c-dim (256)
    int n0 = blockIdx.x * 32;                // x-rows (9216)
    f32x4 acc[2][2] = {};
    for (int k0 = 0; k0 < DIM; k0 += 32) {
        size_t at = (((size_t)(m0 >> 4) * 8 + (k0 >> 5)) << 9) + lane * 8;
        size_t bt = (((size_t)(n0 >> 4) * 8 + (k0 >> 5)) << 9) + lane * 8;
        short8 ah0 = *(const short8*)&Vhi[at];
        short8 al0 = *(const short8*)&Vlo[at];
        short8 ah1 = *(const short8*)&Vhi[at + 4096];
        short8 al1 = *(const short8*)&Vlo[at + 4096];
        short8 bh0 = *(const short8*)&Ahi[bt];
        short8 bl0 = *(const short8*)&Alo[bt];
        short8 bh1 = *(const short8*)&Ahi[bt + 4096];
        short8 bl1 = *(const short8*)&Alo[bt + 4096];
        acc[0][0] = __builtin_amdgcn_mfma_f32_16x16x32_bf16(ah0, bh0, acc[0][0], 0, 0, 0);
        acc[0][0] = __builtin_amdgcn_mfma_f32_16x16x32_bf16(ah0, bl0, acc[0][0], 0, 0, 0);
        acc[0][0] = __builtin_amdgcn_mfma_f32_16x16x32_bf16(al0, bh0, acc[0][0], 0, 0, 0);
        acc[0][1] = __builtin_amdgcn_mfma_f32_16x16x32_bf16(ah0, bh1, acc[0][1], 0, 0, 0);
        acc[0][1] = __builtin_amdgcn_mfma_f32_16x16x32_bf16(ah0, bl1, acc[0][1], 0, 0, 0);
        acc[0][1] = __builtin_amdgcn_mfma_f32_16x16x32_bf16(al0, bh1, acc[0][1], 0, 0, 0);
        acc[1][0] = __builtin_amdgcn_mfma_f32_16x16x32_bf16(ah1, bh0, acc[1][0], 0, 0, 0);
        acc[1][0] = __builtin_amdgcn_mfma_f32_16x16x32_bf16(ah1, bl0, acc[1][0], 0, 0, 0);
        acc[1][0] = __builtin_amdgcn_mfma_f32_16x16x32_bf16(al1, bh0, acc[1][0], 0, 0, 0);
        acc[1][1] = __builtin_amdgcn_mfma_f32_16x16x32_bf16(ah1, bh1, acc[1][1], 0, 0, 0);
        acc[1][1] = __builtin_amdgcn_mfma_f32_16x16x32_bf16(ah1, bl1, acc[1][1], 0, 0, 0);
        acc[1][1] = __builtin_amdgcn_mfma_f32_16x16x32_bf16(al1, bh1, acc[1][1], 0, 0, 0);
    }
    int b = n0 / N;                      // uniform within block
    int kbase = n0 - b * N;
    #pragma unroll
    for (int i = 0; i < 2; ++i)
    #pragma unroll
    for (int r = 0; r < 4; ++r) {
        int m = m0 + i * 16 + quad * 4 + r;
        int h = m >> 5, d = m & 31;
        float bs = bias[m];
        unsigned short* ob = vt + (size_t)(b * NH + h) * ((size_t)N * DH);
        #pragma unroll
        for (int j = 0; j < 2; ++j) {
            int key = kbase + j * 16 + l16;
            ob[foVT(d, key)] = f2bf(acc[i][j][r] + bs);
        }
    }
}

// ---------------- final projection GEMM: fp32 row-major out ----------------
__global__ __launch_bounds__(256) void gemm_p(
    const unsigned short* __restrict__ Ahi, const unsigned short* __restrict__ Alo,
    const unsigned short* __restrict__ Wth, const unsigned short* __restrict__ Wtl,
    const float* __restrict__ bias, float* __restrict__ out)
{
    const unsigned short* Bhi = Wth + (size_t)3 * DIM * DIM;
    const unsigned short* Blo = Wtl + (size_t)3 * DIM * DIM;
    int tid = threadIdx.x;
    int wave = tid >> 6, lane = tid & 63;
    int quad = lane >> 4, l16 = lane & 15;
    int r0 = blockIdx.y * 128 + wave * 32;
    int c0 = blockIdx.x * 32;
    f32x4 acc[2][2] = {};
    for (int k0 = 0; k0 < DIM; k0 += 32) {
        size_t at = (((size_t)(r0 >> 4) * 8 + (k0 >> 5)) << 9) + lane * 8;
        size_t bt = (((size_t)(c0 >> 4) * 8 + (k0 >> 5)) << 9) + lane * 8;
        short8 ah0 = *(const short8*)&Ahi[at];
        short8 al0 = *(const short8*)&Alo[at];
        short8 ah1 = *(const short8*)&Ahi[at + 4096];
        short8 al1 = *(const short8*)&Alo[at + 4096];
        short8 bh0 = *(const short8*)&Bhi[bt];
        short8 bl0 = *(const short8*)&Blo[bt];
        short8 bh1 = *(const short8*)&Bhi[bt + 4096];
        short8 bl1 = *(const short8*)&Blo[bt + 4096];
        acc[0][0] = __builtin_amdgcn_mfma_f32_16x16x32_bf16(ah0, bh0, acc[0][0], 0, 0, 0);
        acc[0][0] = __builtin_amdgcn_mfma_f32_16x16x32_bf16(ah0, bl0, acc[0][0], 0, 0, 0);
        acc[0][0] = __builtin_amdgcn_mfma_f32_16x16x32_bf16(al0, bh0, acc[0][0], 0, 0, 0);
        acc[0][1] = __builtin_amdgcn_mfma_f32_16x16x32_bf16(ah0, bh1, acc[0][1], 0, 0, 0);
        acc[0][1] = __builtin_amdgcn_mfma_f32_16x16x32_bf16(ah0, bl1, acc[0][1], 0, 0, 0);
        acc[0][1] = __builtin_amdgcn_mfma_f32_16x16x32_bf16(al0, bh1, acc[0][1], 0, 0, 0);
        acc[1][0] = __builtin_amdgcn_mfma_f32_16x16x32_bf16(ah1, bh0, acc[1][0], 0, 0, 0);
        acc[1][0] = __builtin_amdgcn_mfma_f32_16x16x32_bf16(ah1, bl0, acc[1][0], 0, 0, 0);
        acc[1][0] = __builtin_amdgcn_mfma_f32_16x16x32_bf16(al1, bh0, acc[1][0], 0, 0, 0);
        acc[1][1] = __builtin_amdgcn_mfma_f32_16x16x32_bf16(ah1, bh1, acc[1][1], 0, 0, 0);
        acc[1][1] = __builtin_amdgcn_mfma_f32_16x16x32_bf16(ah1, bl1, acc[1][1], 0, 0, 0);
        acc[1][1] = __builtin_amdgcn_mfma_f32_16x16x32_bf16(al1, bh1, acc[1][1], 0, 0, 0);
    }
    #pragma unroll
    for (int j = 0; j < 2; ++j) {
        int c = c0 + j * 16 + l16;
        float bs = bias[c];
        #pragma unroll
        for (int i = 0; i < 2; ++i)
        #pragma unroll
        for (int r = 0; r < 4; ++r) {
            int R = r0 + i * 16 + quad * 4 + r;
            out[(size_t)R * DIM + c] = acc[i][j][r] + bs;
        }
    }
}

// ---------------- MFMA flash attention, FragTile operands ------------------
__global__ __launch_bounds__(256) void attn_kernel(
    const unsigned short* __restrict__ Qb,
    const unsigned short* __restrict__ Kb,
    const unsigned short* __restrict__ Vt,
    const float* __restrict__ mask,
    unsigned short* __restrict__ ahn_hi, unsigned short* __restrict__ ahn_lo)
{
    __shared__ unsigned short pbuf[8 * 16 * 40];   // (wave,tile) x 16 x 40
    int tid  = threadIdx.x;
    int wave = tid >> 6, lane = tid & 63;
    int quad = lane >> 4, l16 = lane & 15;
    int bh = blockIdx.y, b = bh >> 3, h = bh & 7;
    int q0 = (blockIdx.x * 4 + wave) * 32;

    const unsigned short* Qf = Qb + (size_t)bh * ((size_t)N * DH);
    const unsigned short* Kf = Kb + (size_t)bh * ((size_t)N * DH);
    const unsigned short* Vf = Vt + (size_t)bh * ((size_t)N * DH);

    short8 qA0 = *(const short8*)&Qf[((size_t)(q0 >> 4) << 9) + lane * 8];
    short8 qA1 = *(const short8*)&Qf[((size_t)((q0 >> 4) + 1) << 9) + lane * 8];

    f32x4 o00 = {0,0,0,0}, o01 = {0,0,0,0}, o10 = {0,0,0,0}, o11 = {0,0,0,0};
    float l0[4] = {0,0,0,0}, l1[4] = {0,0,0,0};

    unsigned short* pb0 = &pbuf[(wave * 2 + 0) * 640];
    unsigned short* pb1 = &pbuf[(wave * 2 + 1) * 640];
    const float* mb = mask + (size_t)b * N;

    for (int k0 = 0; k0 < N; k0 += 32) {
        short8 kB0 = *(const short8*)&Kf[((size_t)(k0 >> 4) << 9) + lane * 8];
        short8 kB1 = *(const short8*)&Kf[((size_t)((k0 >> 4) + 1) << 9) + lane * 8];
        float m0 = mb[k0 + l16] > 0.f ? 1.f : 0.f;
        float m1 = mb[k0 + 16 + l16] > 0.f ? 1.f : 0.f;
        f32x4 z = {0,0,0,0};
        f32x4 s00 = __builtin_amdgcn_mfma_f32_16x16x32_bf16(qA0, kB0, z, 0, 0, 0);
        f32x4 s01 = __builtin_amdgcn_mfma_f32_16x16x32_bf16(qA0, kB1, z, 0, 0, 0);
        f32x4 s10 = __builtin_amdgcn_mfma_f32_16x16x32_bf16(qA1, kB0, z, 0, 0, 0);
        f32x4 s11 = __builtin_amdgcn_mfma_f32_16x16x32_bf16(qA1, kB1, z, 0, 0, 0);
        #pragma unroll
        for (int r = 0; r < 4; ++r) {
            int row = quad * 4 + r;
            float p00 = __expf(s00[r] * m0), p01 = __expf(s01[r] * m1);
            float p10 = __expf(s10[r] * m0), p11 = __expf(s11[r] * m1);
            l0[r] += p00 + p01;
            l1[r] += p10 + p11;
            pb0[row * 40 + l16]      = f2bf(p00);
            pb0[row * 40 + 16 + l16] = f2bf(p01);
            pb1[row * 40 + l16]      = f2bf(p10);
            pb1[row * 40 + 16 + l16] = f2bf(p11);
        }
        short8 vB0 = *(const short8*)&Vf[((size_t)(k0 >> 5) << 9) + lane * 8];
        short8 vB1 = *(const short8*)&Vf[((size_t)((N / 32) + (k0 >> 5)) << 9) + lane * 8];
        short8 pA0 = *(const short8*)&pb0[l16 * 40 + quad * 8];
        short8 pA1 = *(const short8*)&pb1[l16 * 40 + quad * 8];
        o00 = __builtin_amdgcn_mfma_f32_16x16x32_bf16(pA0, vB0, o00, 0, 0, 0);
        o01 = __builtin_amdgcn_mfma_f32_16x16x32_bf16(pA0, vB1, o01, 0, 0, 0);
        o10 = __builtin_amdgcn_mfma_f32_16x16x32_bf16(pA1, vB0, o10, 0, 0, 0);
        o11 = __builtin_amdgcn_mfma_f32_16x16x32_bf16(pA1, vB1, o11, 0, 0, 0);
    }
    #pragma unroll
    for (int r = 0; r < 4; ++r) {
        #pragma unroll
        for (int off = 1; off < 16; off <<= 1) {
            l0[r] += __shfl_xor(l0[r], off, 64);
            l1[r] += __shfl_xor(l1[r], off, 64);
        }
    }
    #pragma unroll
    for (int r = 0; r < 4; ++r) {
        int row = quad * 4 + r;
        float inv0 = 1.f / l0[r], inv1 = 1.f / l1[r];
        int rg0 = b * N + q0 + row;
        int rg1 = b * N + q0 + 16 + row;
        float v00 = o00[r] * inv0, v01 = o01[r] * inv0;
        float v10 = o10[r] * inv1, v11 = o11[r] * inv1;
        unsigned short t;
        size_t o;
        o = fo256(rg0, h * 32 + l16);
        t = f2bf(v00); ahn_hi[o] = t; ahn_lo[o] = f2bf(v00 - bf2f(t));
        o = fo256(rg0, h * 32 + 16 + l16);
        t = f2bf(v01); ahn_hi[o] = t; ahn_lo[o] = f2bf(v01 - bf2f(t));
        o = fo256(rg1, h * 32 + l16);
        t = f2bf(v10); ahn_hi[o] = t; ahn_lo[o] = f2bf(v10 - bf2f(t));
        o = fo256(rg1, h * 32 + 16 + l16);
        t = f2bf(v11); ahn_hi[o] = t; ahn_lo[o] = f2bf(v11 - bf2f(t));
    }
}

extern "C" void kernel_launch(void* const* d_in, const int* in_sizes, int n_in,
                              void* d_out, int out_size, void* d_ws, size_t ws_size,
                              hipStream_t stream)
{
    const float* x    = (const float*)d_in[0];
    const float* mask = (const float*)d_in[1];
    const float* ln_g = (const float*)d_in[2];
    const float* ln_b = (const float*)d_in[3];
    const float* Wq   = (const float*)d_in[4];
    const float* bq   = (const float*)d_in[5];
    const float* Wk   = (const float*)d_in[6];
    const float* bk   = (const float*)d_in[7];
    const float* Wv   = (const float*)d_in[8];
    const float* bv   = (const float*)d_in[9];
    const float* Wp   = (const float*)d_in[10];
    const float* bp   = (const float*)d_in[11];
    float* out = (float*)d_out;

    constexpr size_t SZ  = (size_t)M * DIM;   // 2359296 elements
    constexpr size_t WSZ = (size_t)DIM * DIM; // 65536
    unsigned short* p = (unsigned short*)d_ws;
    unsigned short* xh = p;  p += SZ;
    unsigned short* xl = p;  p += SZ;
    unsigned short* qb = p;  p += SZ;
    unsigned short* kb = p;  p += SZ;
    unsigned short* vt = p;  p += SZ;
    unsigned short* ah = p;  p += SZ;   // attn out hi
    unsigned short* al = p;  p += SZ;   // attn out lo
    unsigned short* wth = p; p += 4 * WSZ;
    unsigned short* wtl = p; p += 4 * WSZ;

    ln_kernel<<<M, 256, 0, stream>>>(x, ln_g, ln_b, xh, xl);

    split_w<<<dim3(8, 8, 4), 256, 0, stream>>>(Wq, Wk, Wv, Wp, wth, wtl);

    gemm_qk<<<dim3(DIM / 32, M / 128, 2), 256, 0, stream>>>(
        xh, xl, wth, wtl, bq, bk, qb, kb);
    gemm_v<<<dim3(M / 32, DIM / 128), 256, 0, stream>>>(
        xh, xl, wth, wtl, bv, vt);

    attn_kernel<<<dim3(N / 128, B * NH), 256, 0, stream>>>(
        qb, kb, vt, mask, ah, al);

    gemm_p<<<dim3(DIM / 32, M / 128), 256, 0, stream>>>(
        ah, al, wth, wtl, bp, out);
}

// Round 6
// 186.516 us; speedup vs baseline: 1.4862x; 1.1539x over previous
//
#include <hip/hip_runtime.h>
#include <math.h>

typedef __attribute__((ext_vector_type(8))) short short8;
typedef __attribute__((ext_vector_type(4))) float f32x4;

constexpr int B   = 4;
constexpr int N   = 2304;
constexpr int DIM = 256;
constexpr int NH  = 8;
constexpr int DH  = 32;
constexpr int M   = B * N;        // 9216 rows

// float -> bf16 round-to-nearest-even, truncation, and back
__device__ inline unsigned short f2bf(float f) {
    union { float f; unsigned u; } c; c.f = f;
    unsigned u = c.u;
    u += 0x7fffu + ((u >> 16) & 1u);
    return (unsigned short)(u >> 16);
}
__device__ inline unsigned short f2bf_trunc(float f) {
    union { float f; unsigned u; } c; c.f = f;
    return (unsigned short)(c.u >> 16);
}
__device__ inline float bf2f(unsigned short h) {
    union { unsigned u; float f; } c; c.u = ((unsigned)h) << 16;
    return c.f;
}

// ---- FragTile layouts: element (row r, contraction k) stored so an MFMA
// A/B-frag load (16 rows x 32 k) is ONE contiguous 1KB wave transaction:
// lane = (k%32/8)*16 + r%16, elem j = k%8.
__device__ inline size_t fo256(int r, int k) {   // [R x 256] tensors
    return ((size_t)((r >> 4) * 8 + (k >> 5)) << 9)
         + (size_t)(((((k & 31) >> 3) << 4) + (r & 15)) * 8 + (k & 7));
}
__device__ inline size_t foQK(int n, int d) {    // per-(b,h) [N x 32]
    return ((size_t)(n >> 4) << 9)
         + (size_t)((((d >> 3) << 4) + (n & 15)) * 8 + (d & 7));
}
__device__ inline size_t foVT(int d, int key) {  // per-(b,h) [32 x N]
    return ((size_t)((d >> 4) * (N / 32) + (key >> 5)) << 9)
         + (size_t)(((((key & 31) >> 3) << 4) + (d & 15)) * 8 + (key & 7));
}

// ---------------- LayerNorm -> hi/lo bf16 FragTile, one block per row ------
__global__ __launch_bounds__(256) void ln_kernel(
    const float* __restrict__ x, const float* __restrict__ g,
    const float* __restrict__ bta,
    unsigned short* __restrict__ xh, unsigned short* __restrict__ xl)
{
    __shared__ float red[4];
    int row = blockIdx.x;
    int t   = threadIdx.x;
    float v = x[(size_t)row * DIM + t];
    float s = v;
    #pragma unroll
    for (int o = 32; o > 0; o >>= 1) s += __shfl_down(s, o, 64);
    if ((t & 63) == 0) red[t >> 6] = s;
    __syncthreads();
    float mu = (red[0] + red[1] + red[2] + red[3]) * (1.0f / DIM);
    __syncthreads();
    float d  = v - mu;
    float s2 = d * d;
    #pragma unroll
    for (int o = 32; o > 0; o >>= 1) s2 += __shfl_down(s2, o, 64);
    if ((t & 63) == 0) red[t >> 6] = s2;
    __syncthreads();
    float var = (red[0] + red[1] + red[2] + red[3]) * (1.0f / DIM);
    float r   = rsqrtf(var + 1e-5f);
    float y   = d * r * g[t] + bta[t];
    unsigned short hh = f2bf(y);
    size_t o = fo256(row, t);
    xh[o] = hh;
    xl[o] = f2bf(y - bf2f(hh));
}

// ---------------- all 4 W (256x256 fp32) -> W^T hi/lo FragTile -------------
__global__ __launch_bounds__(256) void split_w(
    const float* __restrict__ Wq, const float* __restrict__ Wk,
    const float* __restrict__ Wv, const float* __restrict__ Wp,
    unsigned short* __restrict__ Wth, unsigned short* __restrict__ Wtl)
{
    int z = blockIdx.z;
    const float* W = (z == 0) ? Wq : (z == 1) ? Wk : (z == 2) ? Wv : Wp;
    unsigned short* oh = Wth + (size_t)z * DIM * DIM;
    unsigned short* ol = Wtl + (size_t)z * DIM * DIM;
    __shared__ float t[32][33];
    int tid = threadIdx.x;
    int tx = tid & 31, ty0 = tid >> 5;
    int n0 = blockIdx.x * 32, k0 = blockIdx.y * 32;
    for (int ty = ty0; ty < 32; ty += 8)
        t[ty][tx] = W[(size_t)(k0 + ty) * DIM + n0 + tx];
    __syncthreads();
    for (int nn = ty0; nn < 32; nn += 8) {
        float v = t[tx][nn];                 // = W[k0+tx][n0+nn] = Wt[n][k]
        unsigned short hh = f2bf(v);
        size_t o = fo256(n0 + nn, k0 + tx);
        oh[o] = hh;
        ol[o] = f2bf(v - bf2f(hh));
    }
}

// ---------------- fused Q/K/V split-bf16 MFMA GEMM -------------------------
// z=0: Q, z=1: K (A = xn FragTile, B = W^T FragTile, out per-(b,h) QK tiles)
// z=2: V^T  (A = Wv^T FragTile over c, B = xn FragTile over rows)
__global__ __launch_bounds__(256, 4) void gemm_qkv(
    const unsigned short* __restrict__ Ahi, const unsigned short* __restrict__ Alo,
    const unsigned short* __restrict__ Wth, const unsigned short* __restrict__ Wtl,
    const float* __restrict__ bq, const float* __restrict__ bk,
    const float* __restrict__ bv,
    unsigned short* __restrict__ qb, unsigned short* __restrict__ kb,
    unsigned short* __restrict__ vt)
{
    int z = blockIdx.z;
    int bx = blockIdx.x;
    int tid = threadIdx.x;
    int wave = tid >> 6, lane = tid & 63;
    int quad = lane >> 4, l16 = lane & 15;
    const unsigned short* Whi = Wth + (size_t)z * DIM * DIM;
    const unsigned short* Wlo = Wtl + (size_t)z * DIM * DIM;
    int mrow0, ncol0;
    const unsigned short *Phi, *Plo, *Shi, *Slo;
    if (z < 2) {
        mrow0 = (bx >> 3) * 128 + wave * 32;   // xn rows
        ncol0 = (bx & 7) * 32;                 // W^T cols
        Phi = Ahi; Plo = Alo; Shi = Whi; Slo = Wlo;
    } else {
        mrow0 = (bx / 288) * 128 + wave * 32;  // Wv^T rows (c-dim)
        ncol0 = (bx % 288) * 32;               // xn rows
        Phi = Whi; Plo = Wlo; Shi = Ahi; Slo = Alo;
    }
    f32x4 acc[2][2] = {};
    #pragma unroll
    for (int k0 = 0; k0 < DIM; k0 += 32) {
        size_t at = (((size_t)(mrow0 >> 4) * 8 + (k0 >> 5)) << 9) + lane * 8;
        size_t bt = (((size_t)(ncol0 >> 4) * 8 + (k0 >> 5)) << 9) + lane * 8;
        short8 ah0 = *(const short8*)&Phi[at];
        short8 al0 = *(const short8*)&Plo[at];
        short8 ah1 = *(const short8*)&Phi[at + 4096];
        short8 al1 = *(const short8*)&Plo[at + 4096];
        short8 bh0 = *(const short8*)&Shi[bt];
        short8 bl0 = *(const short8*)&Slo[bt];
        short8 bh1 = *(const short8*)&Shi[bt + 4096];
        short8 bl1 = *(const short8*)&Slo[bt + 4096];
        acc[0][0] = __builtin_amdgcn_mfma_f32_16x16x32_bf16(ah0, bh0, acc[0][0], 0, 0, 0);
        acc[0][0] = __builtin_amdgcn_mfma_f32_16x16x32_bf16(ah0, bl0, acc[0][0], 0, 0, 0);
        acc[0][0] = __builtin_amdgcn_mfma_f32_16x16x32_bf16(al0, bh0, acc[0][0], 0, 0, 0);
        acc[0][1] = __builtin_amdgcn_mfma_f32_16x16x32_bf16(ah0, bh1, acc[0][1], 0, 0, 0);
        acc[0][1] = __builtin_amdgcn_mfma_f32_16x16x32_bf16(ah0, bl1, acc[0][1], 0, 0, 0);
        acc[0][1] = __builtin_amdgcn_mfma_f32_16x16x32_bf16(al0, bh1, acc[0][1], 0, 0, 0);
        acc[1][0] = __builtin_amdgcn_mfma_f32_16x16x32_bf16(ah1, bh0, acc[1][0], 0, 0, 0);
        acc[1][0] = __builtin_amdgcn_mfma_f32_16x16x32_bf16(ah1, bl0, acc[1][0], 0, 0, 0);
        acc[1][0] = __builtin_amdgcn_mfma_f32_16x16x32_bf16(al1, bh0, acc[1][0], 0, 0, 0);
        acc[1][1] = __builtin_amdgcn_mfma_f32_16x16x32_bf16(ah1, bh1, acc[1][1], 0, 0, 0);
        acc[1][1] = __builtin_amdgcn_mfma_f32_16x16x32_bf16(ah1, bl1, acc[1][1], 0, 0, 0);
        acc[1][1] = __builtin_amdgcn_mfma_f32_16x16x32_bf16(al1, bh1, acc[1][1], 0, 0, 0);
    }
    if (z < 2) {
        const float* bias = z ? bk : bq;
        unsigned short* out = z ? kb : qb;
        int b = mrow0 / N;
        int nbase = mrow0 - b * N;
        #pragma unroll
        for (int j = 0; j < 2; ++j) {
            int c = ncol0 + j * 16 + l16;
            int h = c >> 5, d = c & 31;
            float bs = bias[c];
            unsigned short* ob = out + (size_t)(b * NH + h) * ((size_t)N * DH);
            #pragma unroll
            for (int i = 0; i < 2; ++i)
            #pragma unroll
            for (int r = 0; r < 4; ++r) {
                int n = nbase + i * 16 + quad * 4 + r;
                ob[foQK(n, d)] = f2bf(acc[i][j][r] + bs);
            }
        }
    } else {
        int b = ncol0 / N;
        int kbase = ncol0 - b * N;
        #pragma unroll
        for (int i = 0; i < 2; ++i)
        #pragma unroll
        for (int r = 0; r < 4; ++r) {
            int m = mrow0 + i * 16 + quad * 4 + r;
            int h = m >> 5, d = m & 31;
            float bs = bv[m];
            unsigned short* ob = vt + (size_t)(b * NH + h) * ((size_t)N * DH);
            #pragma unroll
            for (int j = 0; j < 2; ++j) {
                int key = kbase + j * 16 + l16;
                ob[foVT(d, key)] = f2bf(acc[i][j][r] + bs);
            }
        }
    }
}

// ---------------- final projection GEMM: fp32 row-major out ----------------
// 16-col tiles -> 1152 blocks for occupancy.
__global__ __launch_bounds__(256, 4) void gemm_p(
    const unsigned short* __restrict__ Ahi, const unsigned short* __restrict__ Alo,
    const unsigned short* __restrict__ Wth, const unsigned short* __restrict__ Wtl,
    const float* __restrict__ bias, float* __restrict__ out)
{
    const unsigned short* Bhi = Wth + (size_t)3 * DIM * DIM;
    const unsigned short* Blo = Wtl + (size_t)3 * DIM * DIM;
    int tid = threadIdx.x;
    int wave = tid >> 6, lane = tid & 63;
    int quad = lane >> 4, l16 = lane & 15;
    int r0 = blockIdx.y * 128 + wave * 32;
    int c0 = blockIdx.x * 16;
    f32x4 acc0 = {}, acc1 = {};
    #pragma unroll
    for (int k0 = 0; k0 < DIM; k0 += 32) {
        size_t at = (((size_t)(r0 >> 4) * 8 + (k0 >> 5)) << 9) + lane * 8;
        size_t bt = (((size_t)(c0 >> 4) * 8 + (k0 >> 5)) << 9) + lane * 8;
        short8 ah0 = *(const short8*)&Ahi[at];
        short8 al0 = *(const short8*)&Alo[at];
        short8 ah1 = *(const short8*)&Ahi[at + 4096];
        short8 al1 = *(const short8*)&Alo[at + 4096];
        short8 bh = *(const short8*)&Bhi[bt];
        short8 bl = *(const short8*)&Blo[bt];
        acc0 = __builtin_amdgcn_mfma_f32_16x16x32_bf16(ah0, bh, acc0, 0, 0, 0);
        acc0 = __builtin_amdgcn_mfma_f32_16x16x32_bf16(ah0, bl, acc0, 0, 0, 0);
        acc0 = __builtin_amdgcn_mfma_f32_16x16x32_bf16(al0, bh, acc0, 0, 0, 0);
        acc1 = __builtin_amdgcn_mfma_f32_16x16x32_bf16(ah1, bh, acc1, 0, 0, 0);
        acc1 = __builtin_amdgcn_mfma_f32_16x16x32_bf16(ah1, bl, acc1, 0, 0, 0);
        acc1 = __builtin_amdgcn_mfma_f32_16x16x32_bf16(al1, bh, acc1, 0, 0, 0);
    }
    int c = c0 + l16;
    float bs = bias[c];
    #pragma unroll
    for (int r = 0; r < 4; ++r) {
        int R0 = r0 + quad * 4 + r;
        out[(size_t)R0 * DIM + c] = acc0[r] + bs;
        out[(size_t)(R0 + 16) * DIM + c] = acc1[r] + bs;
    }
}

// ---------------- MFMA flash attention, key-split + prefetch ---------------
// blockIdx.z = key-split half (partials exactly additive: no max-subtraction,
// |s| < ~4). 2-stage prefetch of K/V/mask frags hides L2/L3 latency.
// P stored to LDS with truncation (error through p/sum(p) ratio ~1e-6).
__global__ __launch_bounds__(256, 4) void attn_kernel(
    const unsigned short* __restrict__ Qb,
    const unsigned short* __restrict__ Kb,
    const unsigned short* __restrict__ Vt,
    const float* __restrict__ mask,
    float* __restrict__ po, float* __restrict__ pl)
{
    __shared__ unsigned short pbuf[8 * 16 * 40];   // (wave,tile) x 16 x 40
    int tid  = threadIdx.x;
    int wave = tid >> 6, lane = tid & 63;
    int quad = lane >> 4, l16 = lane & 15;
    int bh = blockIdx.y, b = bh >> 3;
    int sp = blockIdx.z;
    int q0 = (blockIdx.x * 4 + wave) * 32;

    const unsigned short* Qf = Qb + (size_t)bh * ((size_t)N * DH);
    const unsigned short* Kf = Kb + (size_t)bh * ((size_t)N * DH);
    const unsigned short* Vf = Vt + (size_t)bh * ((size_t)N * DH);
    const float* mb = mask + (size_t)b * N;

    short8 qA0 = *(const short8*)&Qf[((size_t)(q0 >> 4) << 9) + lane * 8];
    short8 qA1 = *(const short8*)&Qf[((size_t)((q0 >> 4) + 1) << 9) + lane * 8];

    f32x4 o00 = {0,0,0,0}, o01 = {0,0,0,0}, o10 = {0,0,0,0}, o11 = {0,0,0,0};
    float l0[4] = {0,0,0,0}, l1[4] = {0,0,0,0};

    unsigned short* pb0 = &pbuf[(wave * 2 + 0) * 640];
    unsigned short* pb1 = &pbuf[(wave * 2 + 1) * 640];

    const int kbeg = sp * (N / 2), kend = kbeg + N / 2;

    short8 kB0 = *(const short8*)&Kf[((size_t)(kbeg >> 4) << 9) + lane * 8];
    short8 kB1 = *(const short8*)&Kf[((size_t)((kbeg >> 4) + 1) << 9) + lane * 8];
    short8 vB0 = *(const short8*)&Vf[((size_t)(kbeg >> 5) << 9) + lane * 8];
    short8 vB1 = *(const short8*)&Vf[((size_t)((N / 32) + (kbeg >> 5)) << 9) + lane * 8];
    float m0v = mb[kbeg + l16] > 0.f ? 1.f : 0.f;
    float m1v = mb[kbeg + 16 + l16] > 0.f ? 1.f : 0.f;

    for (int k0 = kbeg; k0 < kend; k0 += 32) {
        // prefetch next chunk (wraparound dummy on last iter keeps it branchless)
        int kn = (k0 + 32 < kend) ? k0 + 32 : kbeg;
        short8 nk0 = *(const short8*)&Kf[((size_t)(kn >> 4) << 9) + lane * 8];
        short8 nk1 = *(const short8*)&Kf[((size_t)((kn >> 4) + 1) << 9) + lane * 8];
        short8 nv0 = *(const short8*)&Vf[((size_t)(kn >> 5) << 9) + lane * 8];
        short8 nv1 = *(const short8*)&Vf[((size_t)((N / 32) + (kn >> 5)) << 9) + lane * 8];
        float nm0 = mb[kn + l16] > 0.f ? 1.f : 0.f;
        float nm1 = mb[kn + 16 + l16] > 0.f ? 1.f : 0.f;

        f32x4 z = {0,0,0,0};
        f32x4 s00 = __builtin_amdgcn_mfma_f32_16x16x32_bf16(qA0, kB0, z, 0, 0, 0);
        f32x4 s01 = __builtin_amdgcn_mfma_f32_16x16x32_bf16(qA0, kB1, z, 0, 0, 0);
        f32x4 s10 = __builtin_amdgcn_mfma_f32_16x16x32_bf16(qA1, kB0, z, 0, 0, 0);
        f32x4 s11 = __builtin_amdgcn_mfma_f32_16x16x32_bf16(qA1, kB1, z, 0, 0, 0);
        #pragma unroll
        for (int r = 0; r < 4; ++r) {
            int row = quad * 4 + r;
            float p00 = __expf(s00[r] * m0v), p01 = __expf(s01[r] * m1v);
            float p10 = __expf(s10[r] * m0v), p11 = __expf(s11[r] * m1v);
            l0[r] += p00 + p01;
            l1[r] += p10 + p11;
            pb0[row * 40 + l16]      = f2bf_trunc(p00);
            pb0[row * 40 + 16 + l16] = f2bf_trunc(p01);
            pb1[row * 40 + l16]      = f2bf_trunc(p10);
            pb1[row * 40 + 16 + l16] = f2bf_trunc(p11);
        }
        short8 pA0 = *(const short8*)&pb0[l16 * 40 + quad * 8];
        short8 pA1 = *(const short8*)&pb1[l16 * 40 + quad * 8];
        o00 = __builtin_amdgcn_mfma_f32_16x16x32_bf16(pA0, vB0, o00, 0, 0, 0);
        o01 = __builtin_amdgcn_mfma_f32_16x16x32_bf16(pA0, vB1, o01, 0, 0, 0);
        o10 = __builtin_amdgcn_mfma_f32_16x16x32_bf16(pA1, vB0, o10, 0, 0, 0);
        o11 = __builtin_amdgcn_mfma_f32_16x16x32_bf16(pA1, vB1, o11, 0, 0, 0);

        kB0 = nk0; kB1 = nk1; vB0 = nv0; vB1 = nv1;
        m0v = nm0; m1v = nm1;
    }
    #pragma unroll
    for (int r = 0; r < 4; ++r) {
        #pragma unroll
        for (int off = 1; off < 16; off <<= 1) {
            l0[r] += __shfl_xor(l0[r], off, 64);
            l1[r] += __shfl_xor(l1[r], off, 64);
        }
    }
    size_t pbase = (size_t)(bh * 2 + sp) * N;
    #pragma unroll
    for (int r = 0; r < 4; ++r) {
        int row = quad * 4 + r;
        size_t b0 = (pbase + q0 + row) * DH;
        size_t b1 = (pbase + q0 + 16 + row) * DH;
        po[b0 + l16]      = o00[r];
        po[b0 + 16 + l16] = o01[r];
        po[b1 + l16]      = o10[r];
        po[b1 + 16 + l16] = o11[r];
        if (l16 == 0) {
            pl[pbase + q0 + row]      = l0[r];
            pl[pbase + q0 + 16 + row] = l1[r];
        }
    }
}

// ---------------- combine key-split partials -> hi/lo FragTile -------------
__global__ __launch_bounds__(256) void combine_kernel(
    const float* __restrict__ po, const float* __restrict__ pl,
    unsigned short* __restrict__ ahn_hi, unsigned short* __restrict__ ahn_lo)
{
    int idx = blockIdx.x * 256 + threadIdx.x;   // [0, B*NH*N*4)
    int bhq = idx >> 2;
    int dg  = (idx & 3) * 8;
    int bh = bhq / N, q = bhq - bh * N;
    int b = bh >> 3, h = bh & 7;
    size_t p0 = ((size_t)(bh * 2 + 0) * N + q) * DH + dg;
    size_t p1 = ((size_t)(bh * 2 + 1) * N + q) * DH + dg;
    float l = pl[(size_t)(bh * 2) * N + q] + pl[(size_t)(bh * 2 + 1) * N + q];
    float inv = 1.f / l;
    float4 a0 = *(const float4*)&po[p0];
    float4 a1 = *(const float4*)&po[p0 + 4];
    float4 c0 = *(const float4*)&po[p1];
    float4 c1 = *(const float4*)&po[p1 + 4];
    float vals[8] = {
        (a0.x + c0.x) * inv, (a0.y + c0.y) * inv,
        (a0.z + c0.z) * inv, (a0.w + c0.w) * inv,
        (a1.x + c1.x) * inv, (a1.y + c1.y) * inv,
        (a1.z + c1.z) * inv, (a1.w + c1.w) * inv };
    union { unsigned short u[8]; short8 v; } hi, lo;
    #pragma unroll
    for (int j = 0; j < 8; ++j) {
        unsigned short t = f2bf(vals[j]);
        hi.u[j] = t;
        lo.u[j] = f2bf(vals[j] - bf2f(t));
    }
    size_t o = fo256(b * N + q, h * 32 + dg);
    *(short8*)&ahn_hi[o] = hi.v;
    *(short8*)&ahn_lo[o] = lo.v;
}

extern "C" void kernel_launch(void* const* d_in, const int* in_sizes, int n_in,
                              void* d_out, int out_size, void* d_ws, size_t ws_size,
                              hipStream_t stream)
{
    const float* x    = (const float*)d_in[0];
    const float* mask = (const float*)d_in[1];
    const float* ln_g = (const float*)d_in[2];
    const float* ln_b = (const float*)d_in[3];
    const float* Wq   = (const float*)d_in[4];
    const float* bq   = (const float*)d_in[5];
    const float* Wk   = (const float*)d_in[6];
    const float* bk   = (const float*)d_in[7];
    const float* Wv   = (const float*)d_in[8];
    const float* bv   = (const float*)d_in[9];
    const float* Wp   = (const float*)d_in[10];
    const float* bp   = (const float*)d_in[11];
    float* out = (float*)d_out;

    constexpr size_t SZ  = (size_t)M * DIM;   // 2359296 elements
    constexpr size_t WSZ = (size_t)DIM * DIM; // 65536
    unsigned short* p = (unsigned short*)d_ws;
    unsigned short* xh = p;  p += SZ;
    unsigned short* xl = p;  p += SZ;
    unsigned short* qb = p;  p += SZ;
    unsigned short* kb = p;  p += SZ;
    unsigned short* vt = p;  p += SZ;
    unsigned short* ah = p;  p += SZ;   // attn out hi
    unsigned short* al = p;  p += SZ;   // attn out lo
    unsigned short* wth = p; p += 4 * WSZ;
    unsigned short* wtl = p; p += 4 * WSZ;
    float* po = (float*)p;                       // B*NH*2*N*DH fp32
    float* pl = po + (size_t)B * NH * 2 * N * DH;

    ln_kernel<<<M, 256, 0, stream>>>(x, ln_g, ln_b, xh, xl);

    split_w<<<dim3(8, 8, 4), 256, 0, stream>>>(Wq, Wk, Wv, Wp, wth, wtl);

    gemm_qkv<<<dim3(576, 1, 3), 256, 0, stream>>>(
        xh, xl, wth, wtl, bq, bk, bv, qb, kb, vt);

    attn_kernel<<<dim3(N / 128, B * NH, 2), 256, 0, stream>>>(
        qb, kb, vt, mask, po, pl);

    combine_kernel<<<(B * NH * N * 4) / 256, 256, 0, stream>>>(po, pl, ah, al);

    gemm_p<<<dim3(DIM / 16, M / 128), 256, 0, stream>>>(
        ah, al, wth, wtl, bp, out);
}